// Round 8
// baseline (282.451 us; speedup 1.0000x reference)
//
#include <hip/hip_runtime.h>
#include <math.h>

#define H 128
#define PC 16     // pool chunks per graph

typedef _Float16 half8v __attribute__((ext_vector_type(8)));
typedef float floatx4 __attribute__((ext_vector_type(4)));

__device__ __forceinline__ int lower_bound_i(const int* a, int n, int key) {
  int lo = 0, hi = n;
  while (lo < hi) { int mid = (lo + hi) >> 1; if (a[mid] < key) lo = mid + 1; else hi = mid; }
  return lo;
}

// zero cntE + slots (must precede k_cpp's count part)
__global__ void k_zero(int* cntE, float* slots, int n) {
  int i = blockIdx.x * 256 + threadIdx.x;
  int stride = gridDim.x * 256;
  for (int j = i; j < n; j += stride) cntE[j] = 0;
  for (int j = i; j < 256; j += stride) slots[j] = 0.f;
}

// merged: blocks [0,EB): count+perm; [EB,EB+128): pack W; rest: prefill esrc pads.
// PW[ct*2048 + ks*512 + quad*128 + n*8 + j] = W[(ks*32+quad*8+j)*128 + ct*16+n]
__global__ void k_cpp(const int* __restrict__ col, int* __restrict__ cntE,
                      int* __restrict__ perm, int E, int EB,
                      const float* __restrict__ W1, const float* __restrict__ W2,
                      _Float16* __restrict__ PW1, _Float16* __restrict__ PW2,
                      int* __restrict__ esrc, int cap, int n, int PB) {
  int b = blockIdx.x;
  int tid = threadIdx.x;
  if (b < EB) {
    int e = b * 256 + tid;
    if (e < E) perm[e] = atomicAdd(&cntE[col[e]], 1);
  } else if (b < EB + 128) {
    int t = (b - EB) * 256 + tid;
    const float* W = (t < 16384) ? W1 : W2;
    _Float16* PW = (t < 16384) ? PW1 : PW2;
    int u = t & 16383;
    int j = u & 7;
    int nn = (u >> 3) & 15;
    int quad = (u >> 7) & 3;
    int ks = (u >> 9) & 3;
    int ct = (u >> 11) & 7;
    PW[u] = (_Float16)W[(ks * 32 + quad * 8 + j) * H + ct * 16 + nn];
  } else {
    int pb = b - EB - 128;
    for (int j = pb * 256 + tid; j < cap; j += PB * 256) esrc[j] = n;  // pad -> zero-node
  }
}

// exclusive scan over c16 = ceil(cnt/16)*16 (16-aligned segments).
__global__ void k_scan_block(const int* __restrict__ cnt, int* __restrict__ offs,
                             int* __restrict__ bsum, int n) {
  __shared__ int s[256];
  int tid = threadIdx.x;
  int i = blockIdx.x * 256 + tid;
  int v = (i < n) ? ((cnt[i] + 15) & ~15) : 0;
  s[tid] = v;
  __syncthreads();
  for (int d = 1; d < 256; d <<= 1) {
    int t = (tid >= d) ? s[tid - d] : 0;
    __syncthreads();
    s[tid] += t;
    __syncthreads();
  }
  if (i < n) offs[i] = s[tid] - v;           // exclusive
  if (tid == 255) bsum[blockIdx.x] = s[255]; // block total
}

// Adds the top-level scan inline: each block sums bsum[0..blockIdx) itself (NB<=256).
__global__ void k_scan_add(int* __restrict__ offs, const int* __restrict__ bsum,
                           const int* __restrict__ cntE, float* __restrict__ dinv, int n) {
  __shared__ int sh[4];
  int tid = threadIdx.x;
  int v = (tid < blockIdx.x) ? bsum[tid] : 0;
#pragma unroll
  for (int o = 32; o > 0; o >>= 1) v += __shfl_xor(v, o, 64);
  if ((tid & 63) == 0) sh[tid >> 6] = v;
  __syncthreads();
  int boff = sh[0] + sh[1] + sh[2] + sh[3];
  int i = blockIdx.x * 256 + tid;
  if (i < n) {
    offs[i] += boff;
    dinv[i] = rsqrtf((float)(cntE[i] + 1));  // +1 for implicit self-loop
  }
}

// GEMM tile (fp32 input, no LN): writes O[ro] = dinv[ro] * (X@W)[ro]  (f16)
__device__ __forceinline__ void gemm_tile_f32(const float* __restrict__ Xf,
                                              const _Float16* __restrict__ PW,
                                              const float* __restrict__ dinv,
                                              _Float16* __restrict__ O,
                                              int wave, int laneid, int n) {
  int m = laneid & 15;
  int quad = laneid >> 4;
  int r0 = wave * 16;
  int row = r0 + m;
  if (row >= n) row = n - 1;
  floatx4 acc[8] = {};
  const half8v* PB8 = (const half8v*)PW;
#pragma unroll
  for (int ks = 0; ks < 4; ks++) {
    int kb = ks * 32 + quad * 8;
    const float* xr = Xf + (size_t)row * H + kb;
    float4 u0 = *(const float4*)xr;
    float4 u1 = *(const float4*)(xr + 4);
    half8v a;
    a[0] = (_Float16)u0.x; a[1] = (_Float16)u0.y; a[2] = (_Float16)u0.z; a[3] = (_Float16)u0.w;
    a[4] = (_Float16)u1.x; a[5] = (_Float16)u1.y; a[6] = (_Float16)u1.z; a[7] = (_Float16)u1.w;
#pragma unroll
    for (int ct = 0; ct < 8; ct++) {
      half8v b = PB8[((ct * 4 + ks) * 4 + quad) * 16 + m];
      acc[ct] = __builtin_amdgcn_mfma_f32_16x16x32_f16(a, b, acc[ct], 0, 0, 0);
    }
  }
  float dv[4];
#pragma unroll
  for (int reg = 0; reg < 4; reg++) {
    int ro = r0 + quad * 4 + reg;
    dv[reg] = (ro < n) ? dinv[ro] : 0.f;
  }
#pragma unroll
  for (int ct = 0; ct < 8; ct++) {
#pragma unroll
    for (int reg = 0; reg < 4; reg++) {
      int ro = r0 + quad * 4 + reg;
      if (ro < n) O[(size_t)ro * H + ct * 16 + m] = (_Float16)(acc[ct][reg] * dv[reg]);
    }
  }
}

// Fused: blocks [0,GB) run gemm1 (x fp32 -> g1 = dinv*(x@W1)); blocks [GB,..) scatter.
// Block 0 also zeroes the zero-node row n of O.
__global__ __launch_bounds__(256) void k_sg1(const int* __restrict__ row, const int* __restrict__ col,
                                             const int* __restrict__ offs, const int* __restrict__ perm,
                                             int* __restrict__ esrc, int E,
                                             const float* __restrict__ Xf,
                                             const _Float16* __restrict__ PW,
                                             const float* __restrict__ dinv,
                                             _Float16* __restrict__ O, int n, int GB) {
  int b = blockIdx.x;
  if (b < GB) {
    if (b == 0 && threadIdx.x < 16) {
      half8v z = {};
      *(half8v*)&O[(size_t)n * H + threadIdx.x * 8] = z;
    }
    int wave = b * 4 + (threadIdx.x >> 6);
    int tiles = (n + 15) >> 4;
    if (wave >= tiles) return;
    gemm_tile_f32(Xf, PW, dinv, O, wave, threadIdx.x & 63, n);
  } else {
    int e = (b - GB) * 256 + threadIdx.x;
    if (e < E) {
      int c = col[e];
      esrc[offs[c] + perm[e]] = row[e];
    }
  }
}

// Layer-2 GEMM: A-load = LN1+ReLU of Xh (mu/rstd from slot butterfly), output scaled by dinv.
// Block 0 zeroes the zero-node row n of O.
__global__ __launch_bounds__(256) void k_gemm2(const _Float16* __restrict__ Xh,
                                               const _Float16* __restrict__ PW,
                                               const float* __restrict__ lnw,
                                               const float* __restrict__ lnb,
                                               const float* __restrict__ slot, float invM,
                                               const float* __restrict__ dinv,
                                               _Float16* __restrict__ O, int n) {
  if (blockIdx.x == 0 && threadIdx.x < 16) {
    half8v z = {};
    *(half8v*)&O[(size_t)n * H + threadIdx.x * 8] = z;
  }
  int wave = blockIdx.x * 4 + (threadIdx.x >> 6);
  int tiles = (n + 15) >> 4;
  if (wave >= tiles) return;
  int lane = threadIdx.x & 63;
  int m = lane & 15;
  int quad = lane >> 4;
  int r0 = wave * 16;
  int row = r0 + m;
  if (row >= n) row = n - 1;

  float s = slot[lane], q = slot[64 + lane];
#pragma unroll
  for (int o = 32; o > 0; o >>= 1) { s += __shfl_xor(s, o, 64); q += __shfl_xor(q, o, 64); }
  float mu = s * invM;
  float var = fmaxf(q * invM - mu * mu, 0.f);
  float rs = 1.f / (sqrtf(var) + 1e-5f);

  floatx4 acc[8] = {};
  const half8v* PB8 = (const half8v*)PW;
#pragma unroll
  for (int ks = 0; ks < 4; ks++) {
    int kb = ks * 32 + quad * 8;
    half8v hv = *(const half8v*)(Xh + (size_t)row * H + kb);
    float4 w0 = *(const float4*)(lnw + kb);
    float4 w1 = *(const float4*)(lnw + kb + 4);
    float4 c0 = *(const float4*)(lnb + kb);
    float4 c1 = *(const float4*)(lnb + kb + 4);
    half8v a;
    a[0] = (_Float16)fmaxf(((float)hv[0] - mu) * rs * w0.x + c0.x, 0.f);
    a[1] = (_Float16)fmaxf(((float)hv[1] - mu) * rs * w0.y + c0.y, 0.f);
    a[2] = (_Float16)fmaxf(((float)hv[2] - mu) * rs * w0.z + c0.z, 0.f);
    a[3] = (_Float16)fmaxf(((float)hv[3] - mu) * rs * w0.w + c0.w, 0.f);
    a[4] = (_Float16)fmaxf(((float)hv[4] - mu) * rs * w1.x + c1.x, 0.f);
    a[5] = (_Float16)fmaxf(((float)hv[5] - mu) * rs * w1.y + c1.y, 0.f);
    a[6] = (_Float16)fmaxf(((float)hv[6] - mu) * rs * w1.z + c1.z, 0.f);
    a[7] = (_Float16)fmaxf(((float)hv[7] - mu) * rs * w1.w + c1.w, 0.f);
#pragma unroll
    for (int ct = 0; ct < 8; ct++) {
      half8v b = PB8[((ct * 4 + ks) * 4 + quad) * 16 + m];
      acc[ct] = __builtin_amdgcn_mfma_f32_16x16x32_f16(a, b, acc[ct], 0, 0, 0);
    }
  }
  float dv[4];
#pragma unroll
  for (int reg = 0; reg < 4; reg++) {
    int ro = r0 + quad * 4 + reg;
    dv[reg] = (ro < n) ? dinv[ro] : 0.f;
  }
#pragma unroll
  for (int ct = 0; ct < 8; ct++) {
#pragma unroll
    for (int reg = 0; reg < 4; reg++) {
      int ro = r0 + quad * 4 + reg;
      if (ro < n) O[(size_t)ro * H + ct * 16 + m] = (_Float16)(acc[ct][reg] * dv[reg]);
    }
  }
}

// Feature-split aggregation: blocks [0,nbh) handle features 0..63, [nbh,2*nbh) features 64..127.
// 8 lanes/node (half8 = 16B each, 128B per half-row), 32 nodes/block, 16-edge bursts.
// Gs holds g = dinv*h (row n = 0); edge lists 16-padded with n.
// Out[i] = dinv[i]*(sum g[s] + g[i]) + bias. LN partials -> slot[0..63],[64..127].
__global__ __launch_bounds__(256) void k_agg(const _Float16* __restrict__ Gs,
                                             _Float16* __restrict__ Out,
                                             const int* __restrict__ esrc, const int* __restrict__ offs,
                                             const int* __restrict__ cntE, const float* __restrict__ dinv,
                                             const float* __restrict__ bias, float* __restrict__ slot,
                                             int n, int nbh) {
  int halfsel = (blockIdx.x >= nbh) ? 1 : 0;
  int nb = blockIdx.x - halfsel * nbh;
  int sub = threadIdx.x >> 3;     // 0..31 node slot within block
  int lane = threadIdx.x & 7;     // 0..7
  int f0 = halfsel * 64 + 8 * lane;
  int i = nb * 32 + sub;
  float sv = 0.f, sq = 0.f;
  if (i < n) {
    float di = dinv[i];
    half8v gself = *(const half8v*)&Gs[(size_t)i * H + f0];
    float acc[8];
#pragma unroll
    for (int e = 0; e < 8; e++) acc[e] = (float)gself[e];
    int beg = offs[i];
    int c16 = (cntE[i] + 15) & ~15;
    int sidA = 0, sidB = 0;
    if (c16 > 0) { sidA = esrc[beg + lane]; sidB = esrc[beg + 8 + lane]; }
    for (int base = 0; base < c16; base += 16) {
      int curA = sidA, curB = sidB;
      if (base + 16 < c16) {
        sidA = esrc[beg + base + 16 + lane];
        sidB = esrc[beg + base + 24 + lane];
      }
      int sg[16]; half8v hg[16];
#pragma unroll
      for (int u = 0; u < 8; u++) {
        sg[u] = __shfl(curA, u, 8);
        sg[8 + u] = __shfl(curB, u, 8);
      }
#pragma unroll
      for (int u = 0; u < 16; u++) hg[u] = *(const half8v*)&Gs[(size_t)sg[u] * H + f0];
#pragma unroll
      for (int e = 0; e < 8; e++) {
        float t0 = 0.f, t1 = 0.f;
#pragma unroll
        for (int u = 0; u < 8; u++) { t0 += (float)hg[u][e]; t1 += (float)hg[8 + u][e]; }
        acc[e] += t0 + t1;
      }
    }
    const float* bb = bias + f0;
    half8v vo;
#pragma unroll
    for (int e = 0; e < 8; e++) {
      float v = di * acc[e] + bb[e];
      vo[e] = (_Float16)v;
      sv += v;
      sq += v * v;
    }
    *(half8v*)&Out[(size_t)i * H + f0] = vo;
  }
#pragma unroll
  for (int o = 32; o > 0; o >>= 1) {
    sv += __shfl_xor(sv, o, 64);
    sq += __shfl_xor(sq, o, 64);
  }
  __shared__ float rsm[4], rqm[4];
  int wave = threadIdx.x >> 6;
  if ((threadIdx.x & 63) == 0) { rsm[wave] = sv; rqm[wave] = sq; }
  __syncthreads();
  if (threadIdx.x == 0) {
    float ts = rsm[0] + rsm[1] + rsm[2] + rsm[3];
    float tq = rqm[0] + rqm[1] + rqm[2] + rqm[3];
    int sl = blockIdx.x & 63;
    atomicAdd(&slot[sl], ts);
    atomicAdd(&slot[64 + sl], tq);
  }
}

// LN2+ReLU fused pooling: PC blocks per graph, private slot per block
// (unconditional store -> no init, no atomics, deterministic).
__global__ __launch_bounds__(128) void k_pool(const _Float16* __restrict__ Hs,
                                              const int* __restrict__ batch,
                                              const float* __restrict__ lnw, const float* __restrict__ lnb,
                                              const float* __restrict__ slot, float invM,
                                              float* __restrict__ psum, int n) {
  int g = blockIdx.x / PC, q = blockIdx.x % PC;
  int t = threadIdx.x;
  int l = t & 63;
  float s = slot[l], qq = slot[64 + l];
#pragma unroll
  for (int o = 32; o > 0; o >>= 1) { s += __shfl_xor(s, o, 64); qq += __shfl_xor(qq, o, 64); }
  float mu = s * invM;
  float var = fmaxf(qq * invM - mu * mu, 0.f);
  float rs = 1.f / (sqrtf(var) + 1e-5f);

  int start = lower_bound_i(batch, n, g);
  int end = lower_bound_i(batch, n, g + 1);
  int tot = end - start;
  int per = (tot + PC - 1) / PC;
  int s0 = start + q * per;
  int e0 = s0 + per; if (e0 > end) e0 = end;
  float w = lnw[t], bb = lnb[t];
  float acc = 0.f;
  for (int i = s0; i < e0; i++) {
    float v = (float)Hs[(size_t)i * H + t];
    v = (v - mu) * rs * w + bb;
    acc += fmaxf(v, 0.f);
  }
  psum[(size_t)blockIdx.x * H + t] = acc;   // unconditional store: no init needed
}

__global__ __launch_bounds__(128) void k_fc(const float* __restrict__ psum, const int* __restrict__ batch,
                                            const float* __restrict__ fcw, const float* __restrict__ fcb,
                                            float* __restrict__ out, int n) {
  int g = blockIdx.x;
  int t = threadIdx.x;
  int start = lower_bound_i(batch, n, g);
  int end = lower_bound_i(batch, n, g + 1);
  float cnt = fmaxf((float)(end - start), 1.f);
  float tot = 0.f;
#pragma unroll
  for (int c = 0; c < PC; c++) tot += psum[(size_t)(g * PC + c) * H + t];
  float v = tot / cnt * fcw[t];
  int lane = t & 63, wave = t >> 6;
#pragma unroll
  for (int o = 32; o > 0; o >>= 1) v += __shfl_xor(v, o, 64);
  __shared__ float r2[2];
  if (lane == 0) r2[wave] = v;
  __syncthreads();
  if (t == 0) {
    float logit = r2[0] + r2[1] + fcb[0];
    out[g] = 1.f / (1.f + expf(-logit));
  }
}

extern "C" void kernel_launch(void* const* d_in, const int* in_sizes, int n_in,
                              void* d_out, int out_size, void* d_ws, size_t ws_size,
                              hipStream_t stream) {
  const float* x    = (const float*)d_in[0];
  const int*   ei   = (const int*)d_in[1];
  const int*   batch= (const int*)d_in[2];
  const float* W1   = (const float*)d_in[3];
  const float* b1   = (const float*)d_in[4];
  const float* ln1w = (const float*)d_in[5];
  const float* ln1b = (const float*)d_in[6];
  const float* W2   = (const float*)d_in[7];
  const float* b2   = (const float*)d_in[8];
  const float* ln2w = (const float*)d_in[9];
  const float* ln2b = (const float*)d_in[10];
  const float* fcw  = (const float*)d_in[11];
  const float* fcb  = (const float*)d_in[12];
  float* out = (float*)d_out;

  int N = in_sizes[2];
  int E = in_sizes[1] / 2;
  int G = out_size;
  int CAP = E + 15 * N;   // upper bound on 16-padded edge total

  char* p = (char*)d_ws;
  int*   cntE   = (int*)p;   p += (size_t)N * 4;
  int*   offs   = (int*)p;   p += (size_t)N * 4;
  float* dinv   = (float*)p; p += (size_t)N * 4;
  int*   perm   = (int*)p;   p += (size_t)E * 4;
  int*   esrc   = (int*)p;   p += (size_t)CAP * 4;
  _Float16* bufA = (_Float16*)p; p += (size_t)(N + 1) * H * 2;  // +1 zero-node row
  _Float16* bufB = (_Float16*)p; p += (size_t)(N + 1) * H * 2;
  _Float16* PW1  = (_Float16*)p; p += 16384 * 2;
  _Float16* PW2  = (_Float16*)p; p += 16384 * 2;
  float* slots  = (float*)p; p += 256 * 4;  // [sum1|sq1|sum2|sq2] x64
  int*   bsum   = (int*)p;   p += 256 * 4;
  float* psum   = (float*)p; p += (size_t)G * PC * H * 4;

  const int* row = ei;
  const int* col = ei + E;

  k_zero<<<256, 256, 0, stream>>>(cntE, slots, N);
  int EB = (E + 255) / 256;
  int PB = 192;
  k_cpp<<<EB + 128 + PB, 256, 0, stream>>>(col, cntE, perm, E, EB,
                                           W1, W2, PW1, PW2, esrc, CAP, N, PB);
  int NB = (N + 255) / 256;
  k_scan_block<<<NB, 256, 0, stream>>>(cntE, offs, bsum, N);
  k_scan_add<<<NB, 256, 0, stream>>>(offs, bsum, cntE, dinv, N);

  int tiles = (N + 15) / 16;
  int GB = (tiles + 3) / 4;
  int NBH = (N + 31) / 32;
  float invM = 1.f / ((float)N * (float)H);

  // scatter + gemm1 fused (gemm1 writes g1 = dinv * (x@W1) in f16; zero-node row cleared)
  k_sg1<<<GB + EB, 256, 0, stream>>>(row, col, offs, perm, esrc, E, x, PW1, dinv, bufA, N, GB);
  k_agg<<<2 * NBH, 256, 0, stream>>>(bufA, bufB, esrc, offs, cntE, dinv, b1, slots, N, NBH);
  // layer 2 (LN1+ReLU fused into gemm A-load; scal from slots; output pre-scaled)
  k_gemm2<<<GB, 256, 0, stream>>>(bufB, PW2, ln1w, ln1b, slots, invM, dinv, bufA, N);
  k_agg<<<2 * NBH, 256, 0, stream>>>(bufA, bufB, esrc, offs, cntE, dinv, b2, slots + 128, N, NBH);
  // pool (LN2+ReLU fused, scal inline, deterministic) + fc + sigmoid
  k_pool<<<G * PC, 128, 0, stream>>>(bufB, batch, ln2w, ln2b, slots + 128, invM, psum, N);
  k_fc<<<G, 128, 0, stream>>>(psum, batch, fcw, fcb, out, N);
}

// Round 9
// 258.238 us; speedup vs baseline: 1.0938x; 1.0938x over previous
//
#include <hip/hip_runtime.h>
#include <math.h>

#define H 128
#define PC 16     // pool chunks per graph

typedef _Float16 half8v __attribute__((ext_vector_type(8)));
typedef float floatx4 __attribute__((ext_vector_type(4)));

__device__ __forceinline__ int lower_bound_i(const int* a, int n, int key) {
  int lo = 0, hi = n;
  while (lo < hi) { int mid = (lo + hi) >> 1; if (a[mid] < key) lo = mid + 1; else hi = mid; }
  return lo;
}

// blocks 0..127: pack W1/W2 into f16 B-fragment order.
// blocks 128..255: zero cntE, slots; prefill esrc with zero-node id n (for 16-padding).
// PW[ct*2048 + ks*512 + quad*128 + n*8 + j] = W[(ks*32+quad*8+j)*128 + ct*16+n]
__global__ void k_initpack(const float* __restrict__ W1, const float* __restrict__ W2,
                           _Float16* __restrict__ PW1, _Float16* __restrict__ PW2,
                           int* cntE, float* slots, int* esrc, int cap, int n) {
  int b = blockIdx.x;
  int tid = threadIdx.x;
  if (b < 128) {
    int t = b * 256 + tid;
    const float* W = (t < 16384) ? W1 : W2;
    _Float16* PW = (t < 16384) ? PW1 : PW2;
    int u = t & 16383;
    int j = u & 7;
    int nn = (u >> 3) & 15;
    int quad = (u >> 7) & 3;
    int ks = (u >> 9) & 3;
    int ct = (u >> 11) & 7;
    PW[u] = (_Float16)W[(ks * 32 + quad * 8 + j) * H + ct * 16 + nn];
  } else {
    int i = (b - 128) * 256 + tid;
    int stride = 128 * 256;
    for (int j = i; j < n; j += stride) cntE[j] = 0;
    for (int j = i; j < 256; j += stride) slots[j] = 0.f;
    for (int j = i; j < cap; j += stride) esrc[j] = n;   // pad -> zero-node
  }
}

// count + record per-edge slot (perm) so scatter needs no atomics.
__global__ void k_count(const int* __restrict__ col, int* __restrict__ cntE,
                        int* __restrict__ perm, int E) {
  int e = blockIdx.x * blockDim.x + threadIdx.x;
  if (e < E) perm[e] = atomicAdd(&cntE[col[e]], 1);
}

// exclusive scan over c16 = ceil(cnt/16)*16 (16-aligned segments).
__global__ void k_scan_block(const int* __restrict__ cnt, int* __restrict__ offs,
                             int* __restrict__ bsum, int n) {
  __shared__ int s[256];
  int tid = threadIdx.x;
  int i = blockIdx.x * 256 + tid;
  int v = (i < n) ? ((cnt[i] + 15) & ~15) : 0;
  s[tid] = v;
  __syncthreads();
  for (int d = 1; d < 256; d <<= 1) {
    int t = (tid >= d) ? s[tid - d] : 0;
    __syncthreads();
    s[tid] += t;
    __syncthreads();
  }
  if (i < n) offs[i] = s[tid] - v;           // exclusive
  if (tid == 255) bsum[blockIdx.x] = s[255]; // block total
}

// Adds the top-level scan inline: each block sums bsum[0..blockIdx) itself (NB<=256).
__global__ void k_scan_add(int* __restrict__ offs, const int* __restrict__ bsum,
                           const int* __restrict__ cntE, float* __restrict__ dinv, int n) {
  __shared__ int sh[4];
  int tid = threadIdx.x;
  int v = (tid < blockIdx.x) ? bsum[tid] : 0;
#pragma unroll
  for (int o = 32; o > 0; o >>= 1) v += __shfl_xor(v, o, 64);
  if ((tid & 63) == 0) sh[tid >> 6] = v;
  __syncthreads();
  int boff = sh[0] + sh[1] + sh[2] + sh[3];
  int i = blockIdx.x * 256 + tid;
  if (i < n) {
    offs[i] += boff;
    dinv[i] = rsqrtf((float)(cntE[i] + 1));  // +1 for implicit self-loop
  }
}

// GEMM tile (fp32 input, no LN): writes O[ro] = dinv[ro] * (X@W)[ro]  (f16)
__device__ __forceinline__ void gemm_tile_f32(const float* __restrict__ Xf,
                                              const _Float16* __restrict__ PW,
                                              const float* __restrict__ dinv,
                                              _Float16* __restrict__ O,
                                              int wave, int laneid, int n) {
  int m = laneid & 15;
  int quad = laneid >> 4;
  int r0 = wave * 16;
  int row = r0 + m;
  if (row >= n) row = n - 1;
  floatx4 acc[8] = {};
  const half8v* PB8 = (const half8v*)PW;
#pragma unroll
  for (int ks = 0; ks < 4; ks++) {
    int kb = ks * 32 + quad * 8;
    const float* xr = Xf + (size_t)row * H + kb;
    float4 u0 = *(const float4*)xr;
    float4 u1 = *(const float4*)(xr + 4);
    half8v a;
    a[0] = (_Float16)u0.x; a[1] = (_Float16)u0.y; a[2] = (_Float16)u0.z; a[3] = (_Float16)u0.w;
    a[4] = (_Float16)u1.x; a[5] = (_Float16)u1.y; a[6] = (_Float16)u1.z; a[7] = (_Float16)u1.w;
#pragma unroll
    for (int ct = 0; ct < 8; ct++) {
      half8v b = PB8[((ct * 4 + ks) * 4 + quad) * 16 + m];
      acc[ct] = __builtin_amdgcn_mfma_f32_16x16x32_f16(a, b, acc[ct], 0, 0, 0);
    }
  }
  float dv[4];
#pragma unroll
  for (int reg = 0; reg < 4; reg++) {
    int ro = r0 + quad * 4 + reg;
    dv[reg] = (ro < n) ? dinv[ro] : 0.f;
  }
#pragma unroll
  for (int ct = 0; ct < 8; ct++) {
#pragma unroll
    for (int reg = 0; reg < 4; reg++) {
      int ro = r0 + quad * 4 + reg;
      if (ro < n) O[(size_t)ro * H + ct * 16 + m] = (_Float16)(acc[ct][reg] * dv[reg]);
    }
  }
}

// Fused: blocks [0,GB) run gemm1 (x fp32 -> g1 = dinv*(x@W1)); blocks [GB,..) scatter.
// Block 0 also zeroes the zero-node row n of O.
__global__ __launch_bounds__(256) void k_sg1(const int* __restrict__ row, const int* __restrict__ col,
                                             const int* __restrict__ offs, const int* __restrict__ perm,
                                             int* __restrict__ esrc, int E,
                                             const float* __restrict__ Xf,
                                             const _Float16* __restrict__ PW,
                                             const float* __restrict__ dinv,
                                             _Float16* __restrict__ O, int n, int GB) {
  int b = blockIdx.x;
  if (b < GB) {
    if (b == 0 && threadIdx.x < 16) {
      half8v z = {};
      *(half8v*)&O[(size_t)n * H + threadIdx.x * 8] = z;
    }
    int wave = b * 4 + (threadIdx.x >> 6);
    int tiles = (n + 15) >> 4;
    if (wave >= tiles) return;
    gemm_tile_f32(Xf, PW, dinv, O, wave, threadIdx.x & 63, n);
  } else {
    int e = (b - GB) * 256 + threadIdx.x;
    if (e < E) {
      int c = col[e];
      esrc[offs[c] + perm[e]] = row[e];
    }
  }
}

// Layer-2 GEMM: A-load = LN1+ReLU of Xh (mu/rstd from slot butterfly), output scaled by dinv.
// Block 0 zeroes the zero-node row n of O.
__global__ __launch_bounds__(256) void k_gemm2(const _Float16* __restrict__ Xh,
                                               const _Float16* __restrict__ PW,
                                               const float* __restrict__ lnw,
                                               const float* __restrict__ lnb,
                                               const float* __restrict__ slot, float invM,
                                               const float* __restrict__ dinv,
                                               _Float16* __restrict__ O, int n) {
  if (blockIdx.x == 0 && threadIdx.x < 16) {
    half8v z = {};
    *(half8v*)&O[(size_t)n * H + threadIdx.x * 8] = z;
  }
  int wave = blockIdx.x * 4 + (threadIdx.x >> 6);
  int tiles = (n + 15) >> 4;
  if (wave >= tiles) return;
  int lane = threadIdx.x & 63;
  int m = lane & 15;
  int quad = lane >> 4;
  int r0 = wave * 16;
  int row = r0 + m;
  if (row >= n) row = n - 1;

  float s = slot[lane], q = slot[64 + lane];
#pragma unroll
  for (int o = 32; o > 0; o >>= 1) { s += __shfl_xor(s, o, 64); q += __shfl_xor(q, o, 64); }
  float mu = s * invM;
  float var = fmaxf(q * invM - mu * mu, 0.f);
  float rs = 1.f / (sqrtf(var) + 1e-5f);

  floatx4 acc[8] = {};
  const half8v* PB8 = (const half8v*)PW;
#pragma unroll
  for (int ks = 0; ks < 4; ks++) {
    int kb = ks * 32 + quad * 8;
    half8v hv = *(const half8v*)(Xh + (size_t)row * H + kb);
    float4 w0 = *(const float4*)(lnw + kb);
    float4 w1 = *(const float4*)(lnw + kb + 4);
    float4 c0 = *(const float4*)(lnb + kb);
    float4 c1 = *(const float4*)(lnb + kb + 4);
    half8v a;
    a[0] = (_Float16)fmaxf(((float)hv[0] - mu) * rs * w0.x + c0.x, 0.f);
    a[1] = (_Float16)fmaxf(((float)hv[1] - mu) * rs * w0.y + c0.y, 0.f);
    a[2] = (_Float16)fmaxf(((float)hv[2] - mu) * rs * w0.z + c0.z, 0.f);
    a[3] = (_Float16)fmaxf(((float)hv[3] - mu) * rs * w0.w + c0.w, 0.f);
    a[4] = (_Float16)fmaxf(((float)hv[4] - mu) * rs * w1.x + c1.x, 0.f);
    a[5] = (_Float16)fmaxf(((float)hv[5] - mu) * rs * w1.y + c1.y, 0.f);
    a[6] = (_Float16)fmaxf(((float)hv[6] - mu) * rs * w1.z + c1.z, 0.f);
    a[7] = (_Float16)fmaxf(((float)hv[7] - mu) * rs * w1.w + c1.w, 0.f);
#pragma unroll
    for (int ct = 0; ct < 8; ct++) {
      half8v b = PB8[((ct * 4 + ks) * 4 + quad) * 16 + m];
      acc[ct] = __builtin_amdgcn_mfma_f32_16x16x32_f16(a, b, acc[ct], 0, 0, 0);
    }
  }
  float dv[4];
#pragma unroll
  for (int reg = 0; reg < 4; reg++) {
    int ro = r0 + quad * 4 + reg;
    dv[reg] = (ro < n) ? dinv[ro] : 0.f;
  }
#pragma unroll
  for (int ct = 0; ct < 8; ct++) {
#pragma unroll
    for (int reg = 0; reg < 4; reg++) {
      int ro = r0 + quad * 4 + reg;
      if (ro < n) O[(size_t)ro * H + ct * 16 + m] = (_Float16)(acc[ct][reg] * dv[reg]);
    }
  }
}

// Gs holds g = dinv*h (pre-scaled rows; row n = 0). Edge lists 16-padded with n.
// Out[i] = dinv[i]*(sum g[s] + g[i]) + bias. Uniform full-16 bursts, sid prefetch.
// LN partial sums -> slot[0..63], slot[64..127].
__global__ __launch_bounds__(256) void k_agg(const _Float16* __restrict__ Gs,
                                             _Float16* __restrict__ Out,
                                             const int* __restrict__ esrc, const int* __restrict__ offs,
                                             const int* __restrict__ cntE, const float* __restrict__ dinv,
                                             const float* __restrict__ bias, float* __restrict__ slot,
                                             int n) {
  int sub = threadIdx.x >> 4;   // 0..15 node slot within block
  int lane = threadIdx.x & 15;
  int i = blockIdx.x * 16 + sub;
  float sv = 0.f, sq = 0.f;
  if (i < n) {
    float di = dinv[i];
    half8v gself = *(const half8v*)&Gs[(size_t)i * H + 8 * lane];
    float acc[8];
#pragma unroll
    for (int e = 0; e < 8; e++) acc[e] = (float)gself[e];
    int beg = offs[i];
    int c16 = (cntE[i] + 15) & ~15;
    int sid = (c16 > 0) ? esrc[beg + lane] : 0;
    for (int base = 0; base < c16; base += 16) {
      int cur = sid;
      if (base + 16 < c16) sid = esrc[beg + base + 16 + lane];
      int sg[16]; half8v hg[16];
#pragma unroll
      for (int u = 0; u < 16; u++) sg[u] = __shfl(cur, u, 16);
#pragma unroll
      for (int u = 0; u < 16; u++) hg[u] = *(const half8v*)&Gs[(size_t)sg[u] * H + 8 * lane];
#pragma unroll
      for (int e = 0; e < 8; e++) {
        float t0 = 0.f, t1 = 0.f;
#pragma unroll
        for (int u = 0; u < 8; u++) { t0 += (float)hg[u][e]; t1 += (float)hg[8 + u][e]; }
        acc[e] += t0 + t1;
      }
    }
    const float* bb = bias + 8 * lane;
    half8v vo;
#pragma unroll
    for (int e = 0; e < 8; e++) {
      float v = di * acc[e] + bb[e];
      vo[e] = (_Float16)v;
      sv += v;
      sq += v * v;
    }
    *(half8v*)&Out[(size_t)i * H + 8 * lane] = vo;
  }
#pragma unroll
  for (int o = 32; o > 0; o >>= 1) {
    sv += __shfl_xor(sv, o, 64);
    sq += __shfl_xor(sq, o, 64);
  }
  __shared__ float rsm[4], rqm[4];
  int wave = threadIdx.x >> 6;
  if ((threadIdx.x & 63) == 0) { rsm[wave] = sv; rqm[wave] = sq; }
  __syncthreads();
  if (threadIdx.x == 0) {
    float ts = rsm[0] + rsm[1] + rsm[2] + rsm[3];
    float tq = rqm[0] + rqm[1] + rqm[2] + rqm[3];
    int sl = blockIdx.x & 63;
    atomicAdd(&slot[sl], ts);
    atomicAdd(&slot[64 + sl], tq);
  }
}

// LN2+ReLU fused pooling: PC blocks per graph, private slot per block
// (unconditional store -> no init, no atomics, deterministic).
__global__ __launch_bounds__(128) void k_pool(const _Float16* __restrict__ Hs,
                                              const int* __restrict__ batch,
                                              const float* __restrict__ lnw, const float* __restrict__ lnb,
                                              const float* __restrict__ slot, float invM,
                                              float* __restrict__ psum, int n) {
  int g = blockIdx.x / PC, q = blockIdx.x % PC;
  int t = threadIdx.x;
  int l = t & 63;
  float s = slot[l], qq = slot[64 + l];
#pragma unroll
  for (int o = 32; o > 0; o >>= 1) { s += __shfl_xor(s, o, 64); qq += __shfl_xor(qq, o, 64); }
  float mu = s * invM;
  float var = fmaxf(qq * invM - mu * mu, 0.f);
  float rs = 1.f / (sqrtf(var) + 1e-5f);

  int start = lower_bound_i(batch, n, g);
  int end = lower_bound_i(batch, n, g + 1);
  int tot = end - start;
  int per = (tot + PC - 1) / PC;
  int s0 = start + q * per;
  int e0 = s0 + per; if (e0 > end) e0 = end;
  float w = lnw[t], bb = lnb[t];
  float acc = 0.f;
  for (int i = s0; i < e0; i++) {
    float v = (float)Hs[(size_t)i * H + t];
    v = (v - mu) * rs * w + bb;
    acc += fmaxf(v, 0.f);
  }
  psum[(size_t)blockIdx.x * H + t] = acc;   // unconditional store: no init needed
}

__global__ __launch_bounds__(128) void k_fc(const float* __restrict__ psum, const int* __restrict__ batch,
                                            const float* __restrict__ fcw, const float* __restrict__ fcb,
                                            float* __restrict__ out, int n) {
  int g = blockIdx.x;
  int t = threadIdx.x;
  int start = lower_bound_i(batch, n, g);
  int end = lower_bound_i(batch, n, g + 1);
  float cnt = fmaxf((float)(end - start), 1.f);
  float tot = 0.f;
#pragma unroll
  for (int c = 0; c < PC; c++) tot += psum[(size_t)(g * PC + c) * H + t];
  float v = tot / cnt * fcw[t];
  int lane = t & 63, wave = t >> 6;
#pragma unroll
  for (int o = 32; o > 0; o >>= 1) v += __shfl_xor(v, o, 64);
  __shared__ float r2[2];
  if (lane == 0) r2[wave] = v;
  __syncthreads();
  if (t == 0) {
    float logit = r2[0] + r2[1] + fcb[0];
    out[g] = 1.f / (1.f + expf(-logit));
  }
}

extern "C" void kernel_launch(void* const* d_in, const int* in_sizes, int n_in,
                              void* d_out, int out_size, void* d_ws, size_t ws_size,
                              hipStream_t stream) {
  const float* x    = (const float*)d_in[0];
  const int*   ei   = (const int*)d_in[1];
  const int*   batch= (const int*)d_in[2];
  const float* W1   = (const float*)d_in[3];
  const float* b1   = (const float*)d_in[4];
  const float* ln1w = (const float*)d_in[5];
  const float* ln1b = (const float*)d_in[6];
  const float* W2   = (const float*)d_in[7];
  const float* b2   = (const float*)d_in[8];
  const float* ln2w = (const float*)d_in[9];
  const float* ln2b = (const float*)d_in[10];
  const float* fcw  = (const float*)d_in[11];
  const float* fcb  = (const float*)d_in[12];
  float* out = (float*)d_out;

  int N = in_sizes[2];
  int E = in_sizes[1] / 2;
  int G = out_size;
  int CAP = E + 15 * N;   // upper bound on 16-padded edge total

  char* p = (char*)d_ws;
  int*   cntE   = (int*)p;   p += (size_t)N * 4;
  int*   offs   = (int*)p;   p += (size_t)N * 4;
  float* dinv   = (float*)p; p += (size_t)N * 4;
  int*   perm   = (int*)p;   p += (size_t)E * 4;
  int*   esrc   = (int*)p;   p += (size_t)CAP * 4;
  _Float16* bufA = (_Float16*)p; p += (size_t)(N + 1) * H * 2;  // +1 zero-node row
  _Float16* bufB = (_Float16*)p; p += (size_t)(N + 1) * H * 2;
  _Float16* PW1  = (_Float16*)p; p += 16384 * 2;
  _Float16* PW2  = (_Float16*)p; p += 16384 * 2;
  float* slots  = (float*)p; p += 256 * 4;  // [sum1|sq1|sum2|sq2] x64
  int*   bsum   = (int*)p;   p += 256 * 4;
  float* psum   = (float*)p; p += (size_t)G * PC * H * 4;

  const int* row = ei;
  const int* col = ei + E;

  k_initpack<<<256, 256, 0, stream>>>(W1, W2, PW1, PW2, cntE, slots, esrc, CAP, N);
  int EB = (E + 255) / 256;
  k_count<<<EB, 256, 0, stream>>>(col, cntE, perm, E);
  int NB = (N + 255) / 256;
  k_scan_block<<<NB, 256, 0, stream>>>(cntE, offs, bsum, N);
  k_scan_add<<<NB, 256, 0, stream>>>(offs, bsum, cntE, dinv, N);

  int tiles = (N + 15) / 16;
  int GB = (tiles + 3) / 4;
  float invM = 1.f / ((float)N * (float)H);

  // scatter + gemm1 fused (gemm1 writes g1 = dinv * (x@W1) in f16; zero-node row cleared)
  k_sg1<<<GB + EB, 256, 0, stream>>>(row, col, offs, perm, esrc, E, x, PW1, dinv, bufA, N, GB);
  k_agg<<<(N + 15) / 16, 256, 0, stream>>>(bufA, bufB, esrc, offs, cntE, dinv, b1, slots, N);
  // layer 2 (LN1+ReLU fused into gemm A-load; scal from slots; output pre-scaled)
  k_gemm2<<<GB, 256, 0, stream>>>(bufB, PW2, ln1w, ln1b, slots, invM, dinv, bufA, N);
  k_agg<<<(N + 15) / 16, 256, 0, stream>>>(bufA, bufB, esrc, offs, cntE, dinv, b2, slots + 128, N);
  // pool (LN2+ReLU fused, scal inline, deterministic) + fc + sigmoid
  k_pool<<<G * PC, 128, 0, stream>>>(bufB, batch, ln2w, ln2b, slots + 128, invM, psum, N);
  k_fc<<<G, 128, 0, stream>>>(psum, batch, fcw, fcb, out, N);
}